// Round 13
// baseline (169.164 us; speedup 1.0000x reference)
//
#include <hip/hip_runtime.h>

typedef __attribute__((ext_vector_type(4))) float f32x4;
typedef __attribute__((ext_vector_type(16))) float f32x16;
typedef __attribute__((ext_vector_type(8))) short bf16x8;
typedef __attribute__((ext_vector_type(4))) unsigned short u16x4;
typedef __attribute__((ext_vector_type(4))) unsigned int u32x4;

#define T_DIM 1024
#define B_DIM 8
#define E_DIM 1024
#define H_DIM 16
#define DH 64

__device__ __forceinline__ unsigned short f2bf(float f) {
  unsigned int u = __builtin_bit_cast(unsigned int, f);
  u += 0x7fffu + ((u >> 16) & 1u);   // RNE
  return (unsigned short)(u >> 16);
}

__device__ __forceinline__ unsigned int cvtpk_bf16(float lo, float hi) {
  unsigned int r;
  asm("v_cvt_pk_bf16_f32 %0, %1, %2" : "=v"(r) : "v"(lo), "v"(hi));
  return r;
}

__device__ __forceinline__ float exp2_hw(float x) {   // bare v_exp_f32 (2^x)
  float r;
  asm("v_exp_f32 %0, %1" : "=v"(r) : "v"(x));
  return r;
}

__device__ __forceinline__ f32x4 mfma16(bf16x8 a, bf16x8 b, f32x4 c) {
  return __builtin_amdgcn_mfma_f32_16x16x32_bf16(a, b, c, 0, 0, 0);
}
__device__ __forceinline__ f32x16 mfma32(bf16x8 a, bf16x8 b, f32x16 c) {
  return __builtin_amdgcn_mfma_f32_32x32x16_bf16(a, b, c, 0, 0, 0);
}

// ---------------- fused cast f32 -> bf16 (all three inputs, one launch) ----------------
__global__ __launch_bounds__(256) void cast_all(
    const float* __restrict__ q, const float* __restrict__ w1,
    const float* __restrict__ w2, unsigned short* __restrict__ dq,
    unsigned short* __restrict__ dw1, unsigned short* __restrict__ dw2) {
  int i = blockIdx.x * 256 + threadIdx.x;   // grid 12288 x 256 = 3145728 float4's
  const float* src;
  unsigned short* dst;
  int off;
  if (i < 2097152)      { src = q;  dst = dq;  off = i; }
  else if (i < 2883584) { src = w1; dst = dw1; off = i - 2097152; }
  else                  { src = w2; dst = dw2; off = i - 2883584; }
  f32x4 v = *(const f32x4*)(src + (size_t)off * 4);
  u16x4 o;
  o[0] = f2bf(v[0]); o[1] = f2bf(v[1]); o[2] = f2bf(v[2]); o[3] = f2bf(v[3]);
  *(u16x4*)(dst + (size_t)off * 4) = o;
}

// ================= GEMM mainloop A (R8/R11, 63.8us measured): BM=128, BN=256, BK=64 =================
// 512 threads = 8 waves (2M x 4N); wave tile 64x64 -> acc[4][4] (64 f32).
// Triple-buffered LDS (3 x 48KB = 144KB), lead-2 staging, counted vmcnt(6).
// XOR swizzle (0 conflicts): linear gload_lds dest; source col 8*((lane&7)^(lane>>3));
// read col unit ((ks*4+lg)^(lr&7)).
__device__ __forceinline__ void mainloop_128x256(
    const unsigned short* __restrict__ Ab,   // A + m0*1024  (rows m0..m0+127)
    const unsigned short* __restrict__ Bb,   // B + n0*1024  (rows n0..n0+255)
    unsigned short* smem, f32x4 acc[4][4]) {
  const int tid = threadIdx.x;
  const int wave = tid >> 6, lane = tid & 63;
  const int lr = lane & 15, lg = lane >> 4;
  const int x7 = lr & 7;
  const int wr = wave >> 2, wc = wave & 3;
  const int rlo = lane >> 3;
  const int csw = 8 * ((lane & 7) ^ rlo);

#define STG(KT, BUF)                                                            \
  {                                                                             \
    unsigned short* la_ = smem + (BUF) * 24576;                                 \
    unsigned short* lb_ = la_ + 8192;                                           \
    _Pragma("unroll")                                                           \
    for (int c_ = 0; c_ < 2; ++c_) {                                            \
      const int ins_ = wave * 2 + c_;                                           \
      __builtin_amdgcn_global_load_lds(                                         \
          (const __attribute__((address_space(1))) void*)(Ab + (size_t)(ins_ * 8 + rlo) * 1024 + (KT) * 64 + csw), \
          (__attribute__((address_space(3))) void*)(la_ + ins_ * 512), 16, 0, 0); \
    }                                                                           \
    _Pragma("unroll")                                                           \
    for (int c_ = 0; c_ < 4; ++c_) {                                            \
      const int ins_ = wave * 4 + c_;                                           \
      __builtin_amdgcn_global_load_lds(                                         \
          (const __attribute__((address_space(1))) void*)(Bb + (size_t)(ins_ * 8 + rlo) * 1024 + (KT) * 64 + csw), \
          (__attribute__((address_space(3))) void*)(lb_ + ins_ * 512), 16, 0, 0); \
    }                                                                           \
  }

#define COMPUTE(BUF)                                                            \
  {                                                                             \
    const unsigned short* la_ = smem + (BUF) * 24576;                           \
    const unsigned short* ha_ = la_ + (wr * 64) * 64;                           \
    const unsigned short* hb_ = la_ + 8192 + (wc * 64) * 64;                    \
    _Pragma("unroll")                                                           \
    for (int ks_ = 0; ks_ < 2; ++ks_) {                                         \
      bf16x8 af_[4], bf_[4];                                                    \
      const int cu_ = (((ks_ * 4 + lg) ^ x7) << 3);                             \
      _Pragma("unroll")                                                         \
      for (int i_ = 0; i_ < 4; ++i_) {                                          \
        af_[i_] = *(const bf16x8*)(ha_ + (i_ * 16 + lr) * 64 + cu_);            \
        bf_[i_] = *(const bf16x8*)(hb_ + (i_ * 16 + lr) * 64 + cu_);            \
      }                                                                         \
      __builtin_amdgcn_s_setprio(1);                                            \
      _Pragma("unroll")                                                         \
      for (int mi_ = 0; mi_ < 4; ++mi_)                                         \
        _Pragma("unroll")                                                       \
        for (int ni_ = 0; ni_ < 4; ++ni_)                                       \
          acc[mi_][ni_] = mfma16(af_[mi_], bf_[ni_], acc[mi_][ni_]);            \
      __builtin_amdgcn_s_setprio(0);                                            \
    }                                                                           \
  }

#define ENDT(WAITSTR)                                                           \
  asm volatile("s_waitcnt " WAITSTR ::: "memory");                              \
  __builtin_amdgcn_s_barrier();                                                 \
  __builtin_amdgcn_sched_barrier(0);

  STG(0, 0) STG(1, 1)
  ENDT("vmcnt(6)")

  for (int tt = 0; tt < 12; tt += 3) {
    STG(tt + 2, 2) COMPUTE(0) ENDT("vmcnt(6)")
    STG(tt + 3, 0) COMPUTE(1) ENDT("vmcnt(6)")
    STG(tt + 4, 1) COMPUTE(2) ENDT("vmcnt(6)")
  }
  STG(14, 2) COMPUTE(0) ENDT("vmcnt(6)")
  STG(15, 0) COMPUTE(1) ENDT("vmcnt(6)")
  COMPUTE(2) ENDT("vmcnt(0)")
  COMPUTE(0)
#undef STG
#undef COMPUTE
#undef ENDT
}

// ===== GEMM mainloop B (R12): BM=128, BN=128, BK=64, 4 waves, 2 blocks/CU =====
__device__ __forceinline__ void mainloop_128x128v2(
    const unsigned short* __restrict__ Ab,   // A + m0*1024
    const unsigned short* __restrict__ Bb,   // B + n0*1024
    unsigned short* smem, f32x4 acc[4][4]) {
  const int tid = threadIdx.x;
  const int wave = tid >> 6, lane = tid & 63;
  const int lr = lane & 15, lg = lane >> 4;
  const int x7 = lr & 7;
  const int wr = wave >> 1, wc = wave & 1;
  const int rlo = lane >> 3;
  const int csw = 8 * ((lane & 7) ^ rlo);

#define STG(KT, BUF)                                                            \
  {                                                                             \
    unsigned short* la_ = smem + (BUF) * 16384;                                 \
    unsigned short* lb_ = la_ + 8192;                                           \
    _Pragma("unroll")                                                           \
    for (int c_ = 0; c_ < 4; ++c_) {                                            \
      const int ins_ = wave * 4 + c_;                                           \
      __builtin_amdgcn_global_load_lds(                                         \
          (const __attribute__((address_space(1))) void*)(Ab + (size_t)(ins_ * 8 + rlo) * 1024 + (KT) * 64 + csw), \
          (__attribute__((address_space(3))) void*)(la_ + ins_ * 512), 16, 0, 0); \
      __builtin_amdgcn_global_load_lds(                                         \
          (const __attribute__((address_space(1))) void*)(Bb + (size_t)(ins_ * 8 + rlo) * 1024 + (KT) * 64 + csw), \
          (__attribute__((address_space(3))) void*)(lb_ + ins_ * 512), 16, 0, 0); \
    }                                                                           \
  }

#define COMPUTE(BUF)                                                            \
  {                                                                             \
    const unsigned short* la_ = smem + (BUF) * 16384;                           \
    const unsigned short* ha_ = la_ + (wr * 64) * 64;                           \
    const unsigned short* hb_ = la_ + 8192 + (wc * 64) * 64;                    \
    _Pragma("unroll")                                                           \
    for (int ks_ = 0; ks_ < 2; ++ks_) {                                         \
      bf16x8 af_[4], bf_[4];                                                    \
      const int cu_ = (((ks_ * 4 + lg) ^ x7) << 3);                             \
      _Pragma("unroll")                                                         \
      for (int i_ = 0; i_ < 4; ++i_) {                                          \
        af_[i_] = *(const bf16x8*)(ha_ + (i_ * 16 + lr) * 64 + cu_);            \
        bf_[i_] = *(const bf16x8*)(hb_ + (i_ * 16 + lr) * 64 + cu_);            \
      }                                                                         \
      __builtin_amdgcn_s_setprio(1);                                            \
      _Pragma("unroll")                                                         \
      for (int mi_ = 0; mi_ < 4; ++mi_)                                         \
        _Pragma("unroll")                                                       \
        for (int ni_ = 0; ni_ < 4; ++ni_)                                       \
          acc[mi_][ni_] = mfma16(af_[mi_], bf_[ni_], acc[mi_][ni_]);            \
      __builtin_amdgcn_s_setprio(0);                                            \
    }                                                                           \
  }

  STG(0, 0)
  asm volatile("s_waitcnt vmcnt(0)" ::: "memory");
  __builtin_amdgcn_s_barrier();
  __builtin_amdgcn_sched_barrier(0);

#pragma unroll 2
  for (int t = 0; t < 16; ++t) {
    if (t < 15) {
      STG(t + 1, (t + 1) & 1)
      asm volatile("s_waitcnt vmcnt(8)" ::: "memory");
    } else {
      asm volatile("s_waitcnt vmcnt(0)" ::: "memory");
    }
    __builtin_amdgcn_s_barrier();
    __builtin_amdgcn_sched_barrier(0);
    COMPUTE(t & 1)
    __builtin_amdgcn_s_barrier();
    __builtin_amdgcn_sched_barrier(0);
  }
#undef STG
#undef COMPUTE
}

// ---------------- GEMM1: qkv proj (R11 structure); V written directly in Vt layout ----------------
// grid 768 = 64 m-tiles x 12 n-tiles = 3.0 exact rounds at 1 block/CU.
// L2 mapping: XCD x owns m-tiles [8x,8x+8), m-minor / n-major.
__global__ __launch_bounds__(512) void gemm_qkv14(
    const unsigned short* __restrict__ A, const unsigned short* __restrict__ W,
    const float* __restrict__ bias,
    unsigned short* __restrict__ Qh, unsigned short* __restrict__ Kh,
    unsigned short* __restrict__ Vt) {
  extern __shared__ unsigned short smem[];
  const int bid = blockIdx.x;
  const int xcd = bid & 7, i = bid >> 3;          // i in [0,96)
  const int m0 = (xcd * 8 + (i & 7)) * 128;       // m-minor within XCD
  const int n0 = (i >> 3) * 256;                  // n-major

  f32x4 acc[4][4];
  const f32x4 z4 = {0.f, 0.f, 0.f, 0.f};
#pragma unroll
  for (int a = 0; a < 4; ++a)
#pragma unroll
    for (int b2 = 0; b2 < 4; ++b2) acc[a][b2] = z4;

  mainloop_128x256(A + (size_t)m0 * 1024, W + (size_t)n0 * 1024, smem, acc);

  const int lane = threadIdx.x & 63, wave = threadIdx.x >> 6;
  const int lr = lane & 15, lg = lane >> 4;
  const int wr = wave >> 2, wc = wave & 3;
#pragma unroll
  for (int mf = 0; mf < 4; ++mf)
#pragma unroll
    for (int nf = 0; nf < 4; ++nf)
#pragma unroll
      for (int j = 0; j < 4; ++j) {
        int m = m0 + wr * 64 + mf * 16 + lg * 4 + j;
        int f = n0 + wc * 64 + nf * 16 + lr;
        float v = acc[mf][nf][j] + bias[f];
        int t = m >> 3, b = m & 7;
        int e = f & 1023, h = e >> 6, d = e & 63;
        int which = f >> 10;
        if (which == 0)
          Qh[((size_t)(b * 16 + h) * T_DIM + t) * DH + d] = f2bf(v * 0.18033688011111772f);  // 0.125*log2(e)
        else if (which == 1)
          Kh[((size_t)(b * 16 + h) * T_DIM + t) * DH + d] = f2bf(v);
        else  // V: write transposed layout directly (kills the transpose kernel)
          Vt[((size_t)(b * 16 + h) * DH + d) * T_DIM + t] = f2bf(v);
      }
}

// ---------------- GEMM2: out = attn @ out_w^T + out_b (f32 out), R12 structure ----------------
// grid 512 = 64 m-tiles x 4 n-tiles = 1.0 exact round at 2 blocks/CU.
__global__ __launch_bounds__(256) void gemm_out13(
    const unsigned short* __restrict__ A, const unsigned short* __restrict__ W,
    const float* __restrict__ bias, float* __restrict__ out) {
  __shared__ unsigned short smem[32768];
  const int bid = blockIdx.x;
  const int xcd = bid & 7, i = bid >> 3;          // i in [0,64)
  const int m0 = (xcd * 8 + (i & 7)) * 128;
  const int n0 = (i >> 3) * 128;

  f32x4 acc[4][4];
  const f32x4 z4 = {0.f, 0.f, 0.f, 0.f};
#pragma unroll
  for (int a = 0; a < 4; ++a)
#pragma unroll
    for (int b2 = 0; b2 < 4; ++b2) acc[a][b2] = z4;

  mainloop_128x128v2(A + (size_t)m0 * 1024, W + (size_t)n0 * 1024, smem, acc);

  const int lane = threadIdx.x & 63, wave = threadIdx.x >> 6;
  const int lr = lane & 15, lg = lane >> 4;
  const int wr = wave >> 1, wc = wave & 1;
#pragma unroll
  for (int mf = 0; mf < 4; ++mf)
#pragma unroll
    for (int nf = 0; nf < 4; ++nf)
#pragma unroll
      for (int j = 0; j < 4; ++j) {
        int m = m0 + wr * 64 + mf * 16 + lg * 4 + j;
        int f = n0 + wc * 64 + nf * 16 + lr;
        out[(size_t)m * E_DIM + f] = acc[mf][nf][j] + bias[f];
      }
}

// ---------------- flash attention v6: block-cooperative coalesced K/V staging ----------------
__global__ __launch_bounds__(256) void flash_attn6(
    const unsigned short* __restrict__ Qh, const unsigned short* __restrict__ Kh,
    const unsigned short* __restrict__ Vt, unsigned short* __restrict__ attn) {
  __shared__ unsigned short lds[2][2][4096];   // [buf][K=0/V=1][64 rows x 64 elems]
  const int tid = threadIdx.x;
  const int wave = tid >> 6, lane = tid & 63;
  const int lq = lane & 31, hi = lane >> 5;
  const int bid = blockIdx.x;
  const int qt = 7 - (bid >> 7);       // heavy q-tiles first
  const int n = bid & 127;
  const int b = n >> 4, h = n & 15;
  const int q0w = qt * 128 + wave * 32;
  const int q = q0w + lq;
  const int nbb = 2 * qt + 2;
  const int mynb = (q0w + 95) >> 6;

  const unsigned short* kh_n = Kh + (size_t)n * (T_DIM * DH);
  const unsigned short* vt_n = Vt + (size_t)n * (DH * T_DIM);

  const int rlo = lane >> 3;
  const int csw = 8 * ((lane & 7) ^ rlo);

#define STAGE(S0, BUF)                                                          \
  {                                                                             \
    _Pragma("unroll")                                                           \
    for (int m_ = 0; m_ < 2; ++m_) {                                            \
      const int instr_ = wave * 2 + m_;                                         \
      const int r_ = instr_ * 8 + rlo;                                          \
      __builtin_amdgcn_global_load_lds(                                         \
          (const __attribute__((address_space(1))) void*)(kh_n + (size_t)((S0) + r_) * DH + csw), \
          (__attribute__((address_space(3))) void*)(&lds[BUF][0][instr_ * 512]), 16, 0, 0); \
      __builtin_amdgcn_global_load_lds(                                         \
          (const __attribute__((address_space(1))) void*)(vt_n + (size_t)r_ * T_DIM + (S0) + csw), \
          (__attribute__((address_space(3))) void*)(&lds[BUF][1][instr_ * 512]), 16, 0, 0); \
    }                                                                           \
  }

  bf16x8 qf[4];
  const unsigned short* qp = Qh + ((size_t)n * T_DIM + q) * DH + hi * 8;
#pragma unroll
  for (int kk = 0; kk < 4; ++kk) qf[kk] = *(const bf16x8*)(qp + kk * 16);

  f32x16 o0, o1;
#pragma unroll
  for (int r = 0; r < 16; ++r) { o0[r] = 0.f; o1[r] = 0.f; }
  float m_run = -1e30f, l_run = 0.f;

  STAGE(0, 0);
  asm volatile("s_waitcnt vmcnt(0)");
  __builtin_amdgcn_s_barrier();

  const int swzr = (lq & 7) << 4;

  for (int i = 0; i < nbb; ++i) {
    const int cur = i & 1;
    if (i + 1 < nbb) {
      STAGE((i + 1) * 64, cur ^ 1);
      asm volatile("s_waitcnt vmcnt(4)");
    } else {
      asm volatile("s_waitcnt vmcnt(0)");
    }
    __builtin_amdgcn_s_barrier();
    __builtin_amdgcn_sched_barrier(0);

    if (i < mynb) {
      const int s0 = i * 64;
      const unsigned short* kb = lds[cur][0];
      const unsigned short* vb = lds[cur][1];
      f32x16 sA, sB;
#pragma unroll
      for (int r = 0; r < 16; ++r) { sA[r] = 0.f; sB[r] = 0.f; }
      __builtin_amdgcn_s_setprio(1);
#pragma unroll
      for (int kk = 0; kk < 4; ++kk) {
        const int cb = ((kk * 32 + hi * 16) ^ swzr) >> 1;
        bf16x8 ka = *(const bf16x8*)(kb + lq * 64 + cb);
        bf16x8 kbf = *(const bf16x8*)(kb + (32 + lq) * 64 + cb);
        sA = mfma32(ka, qf[kk], sA);
        sB = mfma32(kbf, qf[kk], sB);
      }
      __builtin_amdgcn_s_setprio(0);
      if (i == mynb - 1) {
#pragma unroll
        for (int r = 0; r < 16; ++r) {
          int sp = s0 + (r & 3) + 8 * (r >> 2) + 4 * hi;
          if (sp > q)      sA[r] = -10000.0f;
          if (sp + 32 > q) sB[r] = -10000.0f;
        }
      }
      float t0 = fmaxf(sA[0], sB[0]), t1 = fmaxf(sA[1], sB[1]);
      float t2 = fmaxf(sA[2], sB[2]), t3 = fmaxf(sA[3], sB[3]);
#pragma unroll
      for (int r = 4; r < 16; r += 4) {
        t0 = fmaxf(t0, fmaxf(sA[r], sB[r]));
        t1 = fmaxf(t1, fmaxf(sA[r + 1], sB[r + 1]));
        t2 = fmaxf(t2, fmaxf(sA[r + 2], sB[r + 2]));
        t3 = fmaxf(t3, fmaxf(sA[r + 3], sB[r + 3]));
      }
      float tmax = fmaxf(fmaxf(t0, t1), fmaxf(t2, t3));
      tmax = fmaxf(tmax, __shfl_xor(tmax, 32));
      if (__any(tmax - m_run > 11.5f)) {
        float m_new = fmaxf(m_run, tmax);
        float sc = exp2_hw(m_run - m_new);
        l_run *= sc;
#pragma unroll
        for (int r = 0; r < 16; ++r) { o0[r] *= sc; o1[r] *= sc; }
        m_run = m_new;
      }
      float r0 = 0.f, r1 = 0.f, r2 = 0.f, r3 = 0.f;
#pragma unroll
      for (int r = 0; r < 16; r += 4) {
        sA[r] = exp2_hw(sA[r] - m_run);         r0 += sA[r];
        sA[r + 1] = exp2_hw(sA[r + 1] - m_run); r1 += sA[r + 1];
        sA[r + 2] = exp2_hw(sA[r + 2] - m_run); r2 += sA[r + 2];
        sA[r + 3] = exp2_hw(sA[r + 3] - m_run); r3 += sA[r + 3];
      }
#pragma unroll
      for (int r = 0; r < 16; r += 4) {
        sB[r] = exp2_hw(sB[r] - m_run);         r0 += sB[r];
        sB[r + 1] = exp2_hw(sB[r + 1] - m_run); r1 += sB[r + 1];
        sB[r + 2] = exp2_hw(sB[r + 2] - m_run); r2 += sB[r + 2];
        sB[r + 3] = exp2_hw(sB[r + 3] - m_run); r3 += sB[r + 3];
      }
      float rs = (r0 + r1) + (r2 + r3);
      rs += __shfl_xor(rs, 32);
      l_run += rs;
      unsigned int pk[16];
#pragma unroll
      for (int ii = 0; ii < 8; ++ii) pk[ii]     = cvtpk_bf16(sA[2 * ii], sA[2 * ii + 1]);
#pragma unroll
      for (int ii = 0; ii < 8; ++ii) pk[8 + ii] = cvtpk_bf16(sB[2 * ii], sB[2 * ii + 1]);
      __builtin_amdgcn_s_setprio(1);
#pragma unroll
      for (int ks = 0; ks < 4; ++ks) {
        unsigned int A0 = pk[ks * 4 + 0], A1 = pk[ks * 4 + 1];
        unsigned int B0 = pk[ks * 4 + 2], B1 = pk[ks * 4 + 3];
        unsigned int xA0 = __shfl_xor(A0, 32), xA1 = __shfl_xor(A1, 32);
        unsigned int xB0 = __shfl_xor(B0, 32), xB1 = __shfl_xor(B1, 32);
        u32x4 uu;
        uu[0] = hi ? xB0 : A0;
        uu[1] = hi ? xB1 : A1;
        uu[2] = hi ? B0 : xA0;
        uu[3] = hi ? B1 : xA1;
        bf16x8 pf = __builtin_bit_cast(bf16x8, uu);
        const int cb = ((ks * 32 + hi * 16) ^ swzr) >> 1;
        bf16x8 v0 = *(const bf16x8*)(vb + lq * 64 + cb);
        bf16x8 v1 = *(const bf16x8*)(vb + (32 + lq) * 64 + cb);
        o0 = mfma32(v0, pf, o0);
        o1 = mfma32(v1, pf, o1);
      }
      __builtin_amdgcn_s_setprio(0);
    }
    __builtin_amdgcn_s_barrier();
  }
#undef STAGE

  const float inv = 1.0f / l_run;
  unsigned short* op = attn + ((size_t)q * B_DIM + b) * E_DIM + h * DH;
#pragma unroll
  for (int g = 0; g < 4; ++g) {
    u16x4 w0, w1;
#pragma unroll
    for (int jj = 0; jj < 4; ++jj) {
      w0[jj] = f2bf(o0[g * 4 + jj] * inv);
      w1[jj] = f2bf(o1[g * 4 + jj] * inv);
    }
    int d = 8 * g + 4 * hi;
    *(u16x4*)(op + d) = w0;
    *(u16x4*)(op + 32 + d) = w1;
  }
}

extern "C" void kernel_launch(void* const* d_in, const int* in_sizes, int n_in,
                              void* d_out, int out_size, void* d_ws, size_t ws_size,
                              hipStream_t stream) {
  const float* query = (const float*)d_in[0];
  const float* qkv_w = (const float*)d_in[1];
  const float* qkv_b = (const float*)d_in[2];
  const float* out_w = (const float*)d_in[3];
  const float* out_b = (const float*)d_in[4];
  float* out = (float*)d_out;

  char* ws = (char*)d_ws;
  unsigned short* Abf  = (unsigned short*)(ws);
  unsigned short* Wbf  = (unsigned short*)(ws + (size_t)(16u << 20));
  unsigned short* OWbf = (unsigned short*)(ws + (size_t)(22u << 20));
  unsigned short* Qh   = (unsigned short*)(ws + (size_t)(24u << 20));
  unsigned short* Kh   = (unsigned short*)(ws + (size_t)(40u << 20));
  unsigned short* Vt   = (unsigned short*)(ws + (size_t)(72u << 20));
  unsigned short* attn = Abf;  // alias: query-bf16 dead after gemm_qkv14

  cast_all<<<12288, 256, 0, stream>>>(query, qkv_w, out_w, Abf, Wbf, OWbf);
  gemm_qkv14<<<768, 512, 147456, stream>>>(Abf, Wbf, qkv_b, Qh, Kh, Vt);
  flash_attn6<<<1024, 256, 0, stream>>>(Qh, Kh, Vt, attn);
  gemm_out13<<<512, 256, 0, stream>>>(attn, OWbf, out_b, out);
}

// Round 14
// 156.393 us; speedup vs baseline: 1.0817x; 1.0817x over previous
//
#include <hip/hip_runtime.h>

typedef __attribute__((ext_vector_type(4))) float f32x4;
typedef __attribute__((ext_vector_type(16))) float f32x16;
typedef __attribute__((ext_vector_type(8))) short bf16x8;
typedef __attribute__((ext_vector_type(4))) unsigned short u16x4;
typedef __attribute__((ext_vector_type(4))) unsigned int u32x4;

#define T_DIM 1024
#define B_DIM 8
#define E_DIM 1024
#define H_DIM 16
#define DH 64

__device__ __forceinline__ unsigned short f2bf(float f) {
  unsigned int u = __builtin_bit_cast(unsigned int, f);
  u += 0x7fffu + ((u >> 16) & 1u);   // RNE
  return (unsigned short)(u >> 16);
}

__device__ __forceinline__ unsigned int cvtpk_bf16(float lo, float hi) {
  unsigned int r;
  asm("v_cvt_pk_bf16_f32 %0, %1, %2" : "=v"(r) : "v"(lo), "v"(hi));
  return r;
}

__device__ __forceinline__ float exp2_hw(float x) {   // bare v_exp_f32 (2^x)
  float r;
  asm("v_exp_f32 %0, %1" : "=v"(r) : "v"(x));
  return r;
}

__device__ __forceinline__ f32x4 mfma16(bf16x8 a, bf16x8 b, f32x4 c) {
  return __builtin_amdgcn_mfma_f32_16x16x32_bf16(a, b, c, 0, 0, 0);
}
__device__ __forceinline__ f32x16 mfma32(bf16x8 a, bf16x8 b, f32x16 c) {
  return __builtin_amdgcn_mfma_f32_32x32x16_bf16(a, b, c, 0, 0, 0);
}

// ---------------- fused cast f32 -> bf16 (all three inputs, one launch) ----------------
__global__ __launch_bounds__(256) void cast_all(
    const float* __restrict__ q, const float* __restrict__ w1,
    const float* __restrict__ w2, unsigned short* __restrict__ dq,
    unsigned short* __restrict__ dw1, unsigned short* __restrict__ dw2) {
  int i = blockIdx.x * 256 + threadIdx.x;   // grid 12288 x 256 = 3145728 float4's
  const float* src;
  unsigned short* dst;
  int off;
  if (i < 2097152)      { src = q;  dst = dq;  off = i; }
  else if (i < 2883584) { src = w1; dst = dw1; off = i - 2097152; }
  else                  { src = w2; dst = dw2; off = i - 2883584; }
  f32x4 v = *(const f32x4*)(src + (size_t)off * 4);
  u16x4 o;
  o[0] = f2bf(v[0]); o[1] = f2bf(v[1]); o[2] = f2bf(v[2]); o[3] = f2bf(v[3]);
  *(u16x4*)(dst + (size_t)off * 4) = o;
}

// ================= GEMM mainloop A (R8/R11, 63.8us measured): BM=128, BN=256, BK=64 =================
// 512 threads = 8 waves (2M x 4N); wave tile 64x64 -> acc[4][4] (64 f32).
// Triple-buffered LDS (3 x 48KB = 144KB), lead-2 staging, counted vmcnt(6).
// XOR swizzle (0 conflicts): linear gload_lds dest; source col 8*((lane&7)^(lane>>3));
// read col unit ((ks*4+lg)^(lr&7)).
__device__ __forceinline__ void mainloop_128x256(
    const unsigned short* __restrict__ Ab,   // A + m0*1024  (rows m0..m0+127)
    const unsigned short* __restrict__ Bb,   // B + n0*1024  (rows n0..n0+255)
    unsigned short* smem, f32x4 acc[4][4]) {
  const int tid = threadIdx.x;
  const int wave = tid >> 6, lane = tid & 63;
  const int lr = lane & 15, lg = lane >> 4;
  const int x7 = lr & 7;
  const int wr = wave >> 2, wc = wave & 3;
  const int rlo = lane >> 3;
  const int csw = 8 * ((lane & 7) ^ rlo);

#define STG(KT, BUF)                                                            \
  {                                                                             \
    unsigned short* la_ = smem + (BUF) * 24576;                                 \
    unsigned short* lb_ = la_ + 8192;                                           \
    _Pragma("unroll")                                                           \
    for (int c_ = 0; c_ < 2; ++c_) {                                            \
      const int ins_ = wave * 2 + c_;                                           \
      __builtin_amdgcn_global_load_lds(                                         \
          (const __attribute__((address_space(1))) void*)(Ab + (size_t)(ins_ * 8 + rlo) * 1024 + (KT) * 64 + csw), \
          (__attribute__((address_space(3))) void*)(la_ + ins_ * 512), 16, 0, 0); \
    }                                                                           \
    _Pragma("unroll")                                                           \
    for (int c_ = 0; c_ < 4; ++c_) {                                            \
      const int ins_ = wave * 4 + c_;                                           \
      __builtin_amdgcn_global_load_lds(                                         \
          (const __attribute__((address_space(1))) void*)(Bb + (size_t)(ins_ * 8 + rlo) * 1024 + (KT) * 64 + csw), \
          (__attribute__((address_space(3))) void*)(lb_ + ins_ * 512), 16, 0, 0); \
    }                                                                           \
  }

#define COMPUTE(BUF)                                                            \
  {                                                                             \
    const unsigned short* la_ = smem + (BUF) * 24576;                           \
    const unsigned short* ha_ = la_ + (wr * 64) * 64;                           \
    const unsigned short* hb_ = la_ + 8192 + (wc * 64) * 64;                    \
    _Pragma("unroll")                                                           \
    for (int ks_ = 0; ks_ < 2; ++ks_) {                                         \
      bf16x8 af_[4], bf_[4];                                                    \
      const int cu_ = (((ks_ * 4 + lg) ^ x7) << 3);                             \
      _Pragma("unroll")                                                         \
      for (int i_ = 0; i_ < 4; ++i_) {                                          \
        af_[i_] = *(const bf16x8*)(ha_ + (i_ * 16 + lr) * 64 + cu_);            \
        bf_[i_] = *(const bf16x8*)(hb_ + (i_ * 16 + lr) * 64 + cu_);            \
      }                                                                         \
      __builtin_amdgcn_s_setprio(1);                                            \
      _Pragma("unroll")                                                         \
      for (int mi_ = 0; mi_ < 4; ++mi_)                                         \
        _Pragma("unroll")                                                       \
        for (int ni_ = 0; ni_ < 4; ++ni_)                                       \
          acc[mi_][ni_] = mfma16(af_[mi_], bf_[ni_], acc[mi_][ni_]);            \
      __builtin_amdgcn_s_setprio(0);                                            \
    }                                                                           \
  }

#define ENDT(WAITSTR)                                                           \
  asm volatile("s_waitcnt " WAITSTR ::: "memory");                              \
  __builtin_amdgcn_s_barrier();                                                 \
  __builtin_amdgcn_sched_barrier(0);

  STG(0, 0) STG(1, 1)
  ENDT("vmcnt(6)")

  for (int tt = 0; tt < 12; tt += 3) {
    STG(tt + 2, 2) COMPUTE(0) ENDT("vmcnt(6)")
    STG(tt + 3, 0) COMPUTE(1) ENDT("vmcnt(6)")
    STG(tt + 4, 1) COMPUTE(2) ENDT("vmcnt(6)")
  }
  STG(14, 2) COMPUTE(0) ENDT("vmcnt(6)")
  STG(15, 0) COMPUTE(1) ENDT("vmcnt(6)")
  COMPUTE(2) ENDT("vmcnt(0)")
  COMPUTE(0)
#undef STG
#undef COMPUTE
#undef ENDT
}

// ===== GEMM mainloop B (R12): BM=128, BN=128, BK=64, 4 waves, 2 blocks/CU =====
__device__ __forceinline__ void mainloop_128x128v2(
    const unsigned short* __restrict__ Ab,   // A + m0*1024
    const unsigned short* __restrict__ Bb,   // B + n0*1024
    unsigned short* smem, f32x4 acc[4][4]) {
  const int tid = threadIdx.x;
  const int wave = tid >> 6, lane = tid & 63;
  const int lr = lane & 15, lg = lane >> 4;
  const int x7 = lr & 7;
  const int wr = wave >> 1, wc = wave & 1;
  const int rlo = lane >> 3;
  const int csw = 8 * ((lane & 7) ^ rlo);

#define STG(KT, BUF)                                                            \
  {                                                                             \
    unsigned short* la_ = smem + (BUF) * 16384;                                 \
    unsigned short* lb_ = la_ + 8192;                                           \
    _Pragma("unroll")                                                           \
    for (int c_ = 0; c_ < 4; ++c_) {                                            \
      const int ins_ = wave * 4 + c_;                                           \
      __builtin_amdgcn_global_load_lds(                                         \
          (const __attribute__((address_space(1))) void*)(Ab + (size_t)(ins_ * 8 + rlo) * 1024 + (KT) * 64 + csw), \
          (__attribute__((address_space(3))) void*)(la_ + ins_ * 512), 16, 0, 0); \
      __builtin_amdgcn_global_load_lds(                                         \
          (const __attribute__((address_space(1))) void*)(Bb + (size_t)(ins_ * 8 + rlo) * 1024 + (KT) * 64 + csw), \
          (__attribute__((address_space(3))) void*)(lb_ + ins_ * 512), 16, 0, 0); \
    }                                                                           \
  }

#define COMPUTE(BUF)                                                            \
  {                                                                             \
    const unsigned short* la_ = smem + (BUF) * 16384;                           \
    const unsigned short* ha_ = la_ + (wr * 64) * 64;                           \
    const unsigned short* hb_ = la_ + 8192 + (wc * 64) * 64;                    \
    _Pragma("unroll")                                                           \
    for (int ks_ = 0; ks_ < 2; ++ks_) {                                         \
      bf16x8 af_[4], bf_[4];                                                    \
      const int cu_ = (((ks_ * 4 + lg) ^ x7) << 3);                             \
      _Pragma("unroll")                                                         \
      for (int i_ = 0; i_ < 4; ++i_) {                                          \
        af_[i_] = *(const bf16x8*)(ha_ + (i_ * 16 + lr) * 64 + cu_);            \
        bf_[i_] = *(const bf16x8*)(hb_ + (i_ * 16 + lr) * 64 + cu_);            \
      }                                                                         \
      __builtin_amdgcn_s_setprio(1);                                            \
      _Pragma("unroll")                                                         \
      for (int mi_ = 0; mi_ < 4; ++mi_)                                         \
        _Pragma("unroll")                                                       \
        for (int ni_ = 0; ni_ < 4; ++ni_)                                       \
          acc[mi_][ni_] = mfma16(af_[mi_], bf_[ni_], acc[mi_][ni_]);            \
      __builtin_amdgcn_s_setprio(0);                                            \
    }                                                                           \
  }

  STG(0, 0)
  asm volatile("s_waitcnt vmcnt(0)" ::: "memory");
  __builtin_amdgcn_s_barrier();
  __builtin_amdgcn_sched_barrier(0);

#pragma unroll 2
  for (int t = 0; t < 16; ++t) {
    if (t < 15) {
      STG(t + 1, (t + 1) & 1)
      asm volatile("s_waitcnt vmcnt(8)" ::: "memory");
    } else {
      asm volatile("s_waitcnt vmcnt(0)" ::: "memory");
    }
    __builtin_amdgcn_s_barrier();
    __builtin_amdgcn_sched_barrier(0);
    COMPUTE(t & 1)
    __builtin_amdgcn_s_barrier();
    __builtin_amdgcn_sched_barrier(0);
  }
#undef STG
#undef COMPUTE
}

// ---------------- GEMM1: qkv proj (R11 structure, 63.8us), scatter to head layout ----------------
// grid 768 = 64 m-tiles x 12 n-tiles = 3.0 exact rounds at 1 block/CU.
// L2 mapping: XCD x owns m-tiles [8x,8x+8), m-minor / n-major.
__global__ __launch_bounds__(512) void gemm_qkv12(
    const unsigned short* __restrict__ A, const unsigned short* __restrict__ W,
    const float* __restrict__ bias,
    unsigned short* __restrict__ Qh, unsigned short* __restrict__ Kh,
    unsigned short* __restrict__ Vh) {
  extern __shared__ unsigned short smem[];
  const int bid = blockIdx.x;
  const int xcd = bid & 7, i = bid >> 3;          // i in [0,96)
  const int m0 = (xcd * 8 + (i & 7)) * 128;       // m-minor within XCD
  const int n0 = (i >> 3) * 256;                  // n-major

  f32x4 acc[4][4];
  const f32x4 z4 = {0.f, 0.f, 0.f, 0.f};
#pragma unroll
  for (int a = 0; a < 4; ++a)
#pragma unroll
    for (int b2 = 0; b2 < 4; ++b2) acc[a][b2] = z4;

  mainloop_128x256(A + (size_t)m0 * 1024, W + (size_t)n0 * 1024, smem, acc);

  const int lane = threadIdx.x & 63, wave = threadIdx.x >> 6;
  const int lr = lane & 15, lg = lane >> 4;
  const int wr = wave >> 2, wc = wave & 3;
#pragma unroll
  for (int mf = 0; mf < 4; ++mf)
#pragma unroll
    for (int nf = 0; nf < 4; ++nf)
#pragma unroll
      for (int j = 0; j < 4; ++j) {
        int m = m0 + wr * 64 + mf * 16 + lg * 4 + j;
        int f = n0 + wc * 64 + nf * 16 + lr;
        float v = acc[mf][nf][j] + bias[f];
        int t = m >> 3, b = m & 7;
        int e = f & 1023, h = e >> 6, d = e & 63;
        int which = f >> 10;
        size_t idx = ((size_t)(b * 16 + h) * T_DIM + t) * DH + d;
        if (which == 0)      Qh[idx] = f2bf(v * 0.18033688011111772f);  // 0.125*log2(e)
        else if (which == 1) Kh[idx] = f2bf(v);
        else                 Vh[idx] = f2bf(v);
      }
}

// ---------------- GEMM2: out = attn @ out_w^T + out_b (f32 out), R12 structure ----------------
// grid 512 = 64 m-tiles x 4 n-tiles = 1.0 exact round at 2 blocks/CU.
__global__ __launch_bounds__(256) void gemm_out13(
    const unsigned short* __restrict__ A, const unsigned short* __restrict__ W,
    const float* __restrict__ bias, float* __restrict__ out) {
  __shared__ unsigned short smem[32768];
  const int bid = blockIdx.x;
  const int xcd = bid & 7, i = bid >> 3;          // i in [0,64)
  const int m0 = (xcd * 8 + (i & 7)) * 128;
  const int n0 = (i >> 3) * 128;

  f32x4 acc[4][4];
  const f32x4 z4 = {0.f, 0.f, 0.f, 0.f};
#pragma unroll
  for (int a = 0; a < 4; ++a)
#pragma unroll
    for (int b2 = 0; b2 < 4; ++b2) acc[a][b2] = z4;

  mainloop_128x128v2(A + (size_t)m0 * 1024, W + (size_t)n0 * 1024, smem, acc);

  const int lane = threadIdx.x & 63, wave = threadIdx.x >> 6;
  const int lr = lane & 15, lg = lane >> 4;
  const int wr = wave >> 1, wc = wave & 1;
#pragma unroll
  for (int mf = 0; mf < 4; ++mf)
#pragma unroll
    for (int nf = 0; nf < 4; ++nf)
#pragma unroll
      for (int j = 0; j < 4; ++j) {
        int m = m0 + wr * 64 + mf * 16 + lg * 4 + j;
        int f = n0 + wc * 64 + nf * 16 + lr;
        out[(size_t)m * E_DIM + f] = acc[mf][nf][j] + bias[f];
      }
}

// ---------------- V transpose: [n][t][d] -> [n][d][t] ----------------
__global__ __launch_bounds__(256) void transpose_v(
    const unsigned short* __restrict__ Vh, unsigned short* __restrict__ Vt) {
  __shared__ unsigned short tile[64][72];
  const int n = blockIdx.x, t0 = blockIdx.y * 64;
  const int tid = threadIdx.x;
  const int r = tid >> 3, c8 = tid & 7;
#pragma unroll
  for (int it = 0; it < 2; ++it) {
    int row = it * 32 + r;
    bf16x8 v = *(const bf16x8*)(Vh + ((size_t)n * T_DIM + t0 + row) * DH + c8 * 8);
    *(bf16x8*)&tile[row][c8 * 8] = v;
  }
  __syncthreads();
#pragma unroll
  for (int it = 0; it < 2; ++it) {
    int d = it * 32 + r;
    bf16x8 ov;
#pragma unroll
    for (int jj = 0; jj < 8; ++jj) ov[jj] = (short)tile[c8 * 8 + jj][d];
    *(bf16x8*)(Vt + ((size_t)n * DH + d) * T_DIM + t0 + c8 * 8) = ov;
  }
}

// ---------------- flash attention v6: block-cooperative coalesced K/V staging ----------------
__global__ __launch_bounds__(256) void flash_attn6(
    const unsigned short* __restrict__ Qh, const unsigned short* __restrict__ Kh,
    const unsigned short* __restrict__ Vt, unsigned short* __restrict__ attn) {
  __shared__ unsigned short lds[2][2][4096];   // [buf][K=0/V=1][64 rows x 64 elems]
  const int tid = threadIdx.x;
  const int wave = tid >> 6, lane = tid & 63;
  const int lq = lane & 31, hi = lane >> 5;
  const int bid = blockIdx.x;
  const int qt = 7 - (bid >> 7);       // heavy q-tiles first
  const int n = bid & 127;
  const int b = n >> 4, h = n & 15;
  const int q0w = qt * 128 + wave * 32;
  const int q = q0w + lq;
  const int nbb = 2 * qt + 2;
  const int mynb = (q0w + 95) >> 6;

  const unsigned short* kh_n = Kh + (size_t)n * (T_DIM * DH);
  const unsigned short* vt_n = Vt + (size_t)n * (DH * T_DIM);

  const int rlo = lane >> 3;
  const int csw = 8 * ((lane & 7) ^ rlo);

#define STAGE(S0, BUF)                                                          \
  {                                                                             \
    _Pragma("unroll")                                                           \
    for (int m_ = 0; m_ < 2; ++m_) {                                            \
      const int instr_ = wave * 2 + m_;                                         \
      const int r_ = instr_ * 8 + rlo;                                          \
      __builtin_amdgcn_global_load_lds(                                         \
          (const __attribute__((address_space(1))) void*)(kh_n + (size_t)((S0) + r_) * DH + csw), \
          (__attribute__((address_space(3))) void*)(&lds[BUF][0][instr_ * 512]), 16, 0, 0); \
      __builtin_amdgcn_global_load_lds(                                         \
          (const __attribute__((address_space(1))) void*)(vt_n + (size_t)r_ * T_DIM + (S0) + csw), \
          (__attribute__((address_space(3))) void*)(&lds[BUF][1][instr_ * 512]), 16, 0, 0); \
    }                                                                           \
  }

  bf16x8 qf[4];
  const unsigned short* qp = Qh + ((size_t)n * T_DIM + q) * DH + hi * 8;
#pragma unroll
  for (int kk = 0; kk < 4; ++kk) qf[kk] = *(const bf16x8*)(qp + kk * 16);

  f32x16 o0, o1;
#pragma unroll
  for (int r = 0; r < 16; ++r) { o0[r] = 0.f; o1[r] = 0.f; }
  float m_run = -1e30f, l_run = 0.f;

  STAGE(0, 0);
  asm volatile("s_waitcnt vmcnt(0)");
  __builtin_amdgcn_s_barrier();

  const int swzr = (lq & 7) << 4;

  for (int i = 0; i < nbb; ++i) {
    const int cur = i & 1;
    if (i + 1 < nbb) {
      STAGE((i + 1) * 64, cur ^ 1);
      asm volatile("s_waitcnt vmcnt(4)");
    } else {
      asm volatile("s_waitcnt vmcnt(0)");
    }
    __builtin_amdgcn_s_barrier();
    __builtin_amdgcn_sched_barrier(0);

    if (i < mynb) {
      const int s0 = i * 64;
      const unsigned short* kb = lds[cur][0];
      const unsigned short* vb = lds[cur][1];
      f32x16 sA, sB;
#pragma unroll
      for (int r = 0; r < 16; ++r) { sA[r] = 0.f; sB[r] = 0.f; }
      __builtin_amdgcn_s_setprio(1);
#pragma unroll
      for (int kk = 0; kk < 4; ++kk) {
        const int cb = ((kk * 32 + hi * 16) ^ swzr) >> 1;
        bf16x8 ka = *(const bf16x8*)(kb + lq * 64 + cb);
        bf16x8 kbf = *(const bf16x8*)(kb + (32 + lq) * 64 + cb);
        sA = mfma32(ka, qf[kk], sA);
        sB = mfma32(kbf, qf[kk], sB);
      }
      __builtin_amdgcn_s_setprio(0);
      if (i == mynb - 1) {
#pragma unroll
        for (int r = 0; r < 16; ++r) {
          int sp = s0 + (r & 3) + 8 * (r >> 2) + 4 * hi;
          if (sp > q)      sA[r] = -10000.0f;
          if (sp + 32 > q) sB[r] = -10000.0f;
        }
      }
      float t0 = fmaxf(sA[0], sB[0]), t1 = fmaxf(sA[1], sB[1]);
      float t2 = fmaxf(sA[2], sB[2]), t3 = fmaxf(sA[3], sB[3]);
#pragma unroll
      for (int r = 4; r < 16; r += 4) {
        t0 = fmaxf(t0, fmaxf(sA[r], sB[r]));
        t1 = fmaxf(t1, fmaxf(sA[r + 1], sB[r + 1]));
        t2 = fmaxf(t2, fmaxf(sA[r + 2], sB[r + 2]));
        t3 = fmaxf(t3, fmaxf(sA[r + 3], sB[r + 3]));
      }
      float tmax = fmaxf(fmaxf(t0, t1), fmaxf(t2, t3));
      tmax = fmaxf(tmax, __shfl_xor(tmax, 32));
      if (__any(tmax - m_run > 11.5f)) {
        float m_new = fmaxf(m_run, tmax);
        float sc = exp2_hw(m_run - m_new);
        l_run *= sc;
#pragma unroll
        for (int r = 0; r < 16; ++r) { o0[r] *= sc; o1[r] *= sc; }
        m_run = m_new;
      }
      float r0 = 0.f, r1 = 0.f, r2 = 0.f, r3 = 0.f;
#pragma unroll
      for (int r = 0; r < 16; r += 4) {
        sA[r] = exp2_hw(sA[r] - m_run);         r0 += sA[r];
        sA[r + 1] = exp2_hw(sA[r + 1] - m_run); r1 += sA[r + 1];
        sA[r + 2] = exp2_hw(sA[r + 2] - m_run); r2 += sA[r + 2];
        sA[r + 3] = exp2_hw(sA[r + 3] - m_run); r3 += sA[r + 3];
      }
#pragma unroll
      for (int r = 0; r < 16; r += 4) {
        sB[r] = exp2_hw(sB[r] - m_run);         r0 += sB[r];
        sB[r + 1] = exp2_hw(sB[r + 1] - m_run); r1 += sB[r + 1];
        sB[r + 2] = exp2_hw(sB[r + 2] - m_run); r2 += sB[r + 2];
        sB[r + 3] = exp2_hw(sB[r + 3] - m_run); r3 += sB[r + 3];
      }
      float rs = (r0 + r1) + (r2 + r3);
      rs += __shfl_xor(rs, 32);
      l_run += rs;
      unsigned int pk[16];
#pragma unroll
      for (int ii = 0; ii < 8; ++ii) pk[ii]     = cvtpk_bf16(sA[2 * ii], sA[2 * ii + 1]);
#pragma unroll
      for (int ii = 0; ii < 8; ++ii) pk[8 + ii] = cvtpk_bf16(sB[2 * ii], sB[2 * ii + 1]);
      __builtin_amdgcn_s_setprio(1);
#pragma unroll
      for (int ks = 0; ks < 4; ++ks) {
        unsigned int A0 = pk[ks * 4 + 0], A1 = pk[ks * 4 + 1];
        unsigned int B0 = pk[ks * 4 + 2], B1 = pk[ks * 4 + 3];
        unsigned int xA0 = __shfl_xor(A0, 32), xA1 = __shfl_xor(A1, 32);
        unsigned int xB0 = __shfl_xor(B0, 32), xB1 = __shfl_xor(B1, 32);
        u32x4 uu;
        uu[0] = hi ? xB0 : A0;
        uu[1] = hi ? xB1 : A1;
        uu[2] = hi ? B0 : xA0;
        uu[3] = hi ? B1 : xA1;
        bf16x8 pf = __builtin_bit_cast(bf16x8, uu);
        const int cb = ((ks * 32 + hi * 16) ^ swzr) >> 1;
        bf16x8 v0 = *(const bf16x8*)(vb + lq * 64 + cb);
        bf16x8 v1 = *(const bf16x8*)(vb + (32 + lq) * 64 + cb);
        o0 = mfma32(v0, pf, o0);
        o1 = mfma32(v1, pf, o1);
      }
      __builtin_amdgcn_s_setprio(0);
    }
    __builtin_amdgcn_s_barrier();
  }
#undef STAGE

  const float inv = 1.0f / l_run;
  unsigned short* op = attn + ((size_t)q * B_DIM + b) * E_DIM + h * DH;
#pragma unroll
  for (int g = 0; g < 4; ++g) {
    u16x4 w0, w1;
#pragma unroll
    for (int jj = 0; jj < 4; ++jj) {
      w0[jj] = f2bf(o0[g * 4 + jj] * inv);
      w1[jj] = f2bf(o1[g * 4 + jj] * inv);
    }
    int d = 8 * g + 4 * hi;
    *(u16x4*)(op + d) = w0;
    *(u16x4*)(op + 32 + d) = w1;
  }
}

extern "C" void kernel_launch(void* const* d_in, const int* in_sizes, int n_in,
                              void* d_out, int out_size, void* d_ws, size_t ws_size,
                              hipStream_t stream) {
  const float* query = (const float*)d_in[0];
  const float* qkv_w = (const float*)d_in[1];
  const float* qkv_b = (const float*)d_in[2];
  const float* out_w = (const float*)d_in[3];
  const float* out_b = (const float*)d_in[4];
  float* out = (float*)d_out;

  char* ws = (char*)d_ws;
  unsigned short* Abf  = (unsigned short*)(ws);
  unsigned short* Wbf  = (unsigned short*)(ws + (size_t)(16u << 20));
  unsigned short* OWbf = (unsigned short*)(ws + (size_t)(22u << 20));
  unsigned short* Qh   = (unsigned short*)(ws + (size_t)(24u << 20));
  unsigned short* Kh   = (unsigned short*)(ws + (size_t)(40u << 20));
  unsigned short* Vh   = (unsigned short*)(ws + (size_t)(56u << 20));
  unsigned short* Vt   = (unsigned short*)(ws + (size_t)(72u << 20));
  unsigned short* attn = Abf;  // alias: query-bf16 dead after gemm_qkv12

  cast_all<<<12288, 256, 0, stream>>>(query, qkv_w, out_w, Abf, Wbf, OWbf);
  gemm_qkv12<<<768, 512, 147456, stream>>>(Abf, Wbf, qkv_b, Qh, Kh, Vh);
  transpose_v<<<dim3(128, 16), 256, 0, stream>>>(Vh, Vt);
  flash_attn6<<<1024, 256, 0, stream>>>(Qh, Kh, Vt, attn);
  gemm_out13<<<512, 256, 0, stream>>>(attn, OWbf, out_b, out);
}

// Round 15
// 146.439 us; speedup vs baseline: 1.1552x; 1.0680x over previous
//
#include <hip/hip_runtime.h>

typedef __attribute__((ext_vector_type(4))) float f32x4;
typedef __attribute__((ext_vector_type(16))) float f32x16;
typedef __attribute__((ext_vector_type(8))) short bf16x8;
typedef __attribute__((ext_vector_type(4))) unsigned short u16x4;
typedef __attribute__((ext_vector_type(4))) unsigned int u32x4;

#define T_DIM 1024
#define B_DIM 8
#define E_DIM 1024
#define H_DIM 16
#define DH 64

__device__ __forceinline__ unsigned short f2bf(float f) {
  unsigned int u = __builtin_bit_cast(unsigned int, f);
  u += 0x7fffu + ((u >> 16) & 1u);   // RNE
  return (unsigned short)(u >> 16);
}

__device__ __forceinline__ unsigned int cvtpk_bf16(float lo, float hi) {
  unsigned int r;
  asm("v_cvt_pk_bf16_f32 %0, %1, %2" : "=v"(r) : "v"(lo), "v"(hi));
  return r;
}

__device__ __forceinline__ float exp2_hw(float x) {   // bare v_exp_f32 (2^x)
  float r;
  asm("v_exp_f32 %0, %1" : "=v"(r) : "v"(x));
  return r;
}

__device__ __forceinline__ f32x4 mfma16(bf16x8 a, bf16x8 b, f32x4 c) {
  return __builtin_amdgcn_mfma_f32_16x16x32_bf16(a, b, c, 0, 0, 0);
}
__device__ __forceinline__ f32x16 mfma32(bf16x8 a, bf16x8 b, f32x16 c) {
  return __builtin_amdgcn_mfma_f32_32x32x16_bf16(a, b, c, 0, 0, 0);
}

// ---------------- fused cast f32 -> bf16 (all three inputs, one launch) ----------------
__global__ __launch_bounds__(256) void cast_all(
    const float* __restrict__ q, const float* __restrict__ w1,
    const float* __restrict__ w2, unsigned short* __restrict__ dq,
    unsigned short* __restrict__ dw1, unsigned short* __restrict__ dw2) {
  int i = blockIdx.x * 256 + threadIdx.x;   // grid 12288 x 256 = 3145728 float4's
  const float* src;
  unsigned short* dst;
  int off;
  if (i < 2097152)      { src = q;  dst = dq;  off = i; }
  else if (i < 2883584) { src = w1; dst = dw1; off = i - 2097152; }
  else                  { src = w2; dst = dw2; off = i - 2883584; }
  f32x4 v = *(const f32x4*)(src + (size_t)off * 4);
  u16x4 o;
  o[0] = f2bf(v[0]); o[1] = f2bf(v[1]); o[2] = f2bf(v[2]); o[3] = f2bf(v[3]);
  *(u16x4*)(dst + (size_t)off * 4) = o;
}

// ================= GEMM mainloop A (R8/R11, 63.8us measured): BM=128, BN=256, BK=64 =================
// 512 threads = 8 waves (2M x 4N); wave tile 64x64 -> acc[4][4] (64 f32).
// Triple-buffered LDS (3 x 48KB = 144KB), lead-2 staging, counted vmcnt(6).
// XOR swizzle (0 conflicts): linear gload_lds dest; source col 8*((lane&7)^(lane>>3));
// read col unit ((ks*4+lg)^(lr&7)).
__device__ __forceinline__ void mainloop_128x256(
    const unsigned short* __restrict__ Ab,   // A + m0*1024  (rows m0..m0+127)
    const unsigned short* __restrict__ Bb,   // B + n0*1024  (rows n0..n0+255)
    unsigned short* smem, f32x4 acc[4][4]) {
  const int tid = threadIdx.x;
  const int wave = tid >> 6, lane = tid & 63;
  const int lr = lane & 15, lg = lane >> 4;
  const int x7 = lr & 7;
  const int wr = wave >> 2, wc = wave & 3;
  const int rlo = lane >> 3;
  const int csw = 8 * ((lane & 7) ^ rlo);

#define STG(KT, BUF)                                                            \
  {                                                                             \
    unsigned short* la_ = smem + (BUF) * 24576;                                 \
    unsigned short* lb_ = la_ + 8192;                                           \
    _Pragma("unroll")                                                           \
    for (int c_ = 0; c_ < 2; ++c_) {                                            \
      const int ins_ = wave * 2 + c_;                                           \
      __builtin_amdgcn_global_load_lds(                                         \
          (const __attribute__((address_space(1))) void*)(Ab + (size_t)(ins_ * 8 + rlo) * 1024 + (KT) * 64 + csw), \
          (__attribute__((address_space(3))) void*)(la_ + ins_ * 512), 16, 0, 0); \
    }                                                                           \
    _Pragma("unroll")                                                           \
    for (int c_ = 0; c_ < 4; ++c_) {                                            \
      const int ins_ = wave * 4 + c_;                                           \
      __builtin_amdgcn_global_load_lds(                                         \
          (const __attribute__((address_space(1))) void*)(Bb + (size_t)(ins_ * 8 + rlo) * 1024 + (KT) * 64 + csw), \
          (__attribute__((address_space(3))) void*)(lb_ + ins_ * 512), 16, 0, 0); \
    }                                                                           \
  }

#define COMPUTE(BUF)                                                            \
  {                                                                             \
    const unsigned short* la_ = smem + (BUF) * 24576;                           \
    const unsigned short* ha_ = la_ + (wr * 64) * 64;                           \
    const unsigned short* hb_ = la_ + 8192 + (wc * 64) * 64;                    \
    _Pragma("unroll")                                                           \
    for (int ks_ = 0; ks_ < 2; ++ks_) {                                         \
      bf16x8 af_[4], bf_[4];                                                    \
      const int cu_ = (((ks_ * 4 + lg) ^ x7) << 3);                             \
      _Pragma("unroll")                                                         \
      for (int i_ = 0; i_ < 4; ++i_) {                                          \
        af_[i_] = *(const bf16x8*)(ha_ + (i_ * 16 + lr) * 64 + cu_);            \
        bf_[i_] = *(const bf16x8*)(hb_ + (i_ * 16 + lr) * 64 + cu_);            \
      }                                                                         \
      __builtin_amdgcn_s_setprio(1);                                            \
      _Pragma("unroll")                                                         \
      for (int mi_ = 0; mi_ < 4; ++mi_)                                         \
        _Pragma("unroll")                                                       \
        for (int ni_ = 0; ni_ < 4; ++ni_)                                       \
          acc[mi_][ni_] = mfma16(af_[mi_], bf_[ni_], acc[mi_][ni_]);            \
      __builtin_amdgcn_s_setprio(0);                                            \
    }                                                                           \
  }

#define ENDT(WAITSTR)                                                           \
  asm volatile("s_waitcnt " WAITSTR ::: "memory");                              \
  __builtin_amdgcn_s_barrier();                                                 \
  __builtin_amdgcn_sched_barrier(0);

  STG(0, 0) STG(1, 1)
  ENDT("vmcnt(6)")

  for (int tt = 0; tt < 12; tt += 3) {
    STG(tt + 2, 2) COMPUTE(0) ENDT("vmcnt(6)")
    STG(tt + 3, 0) COMPUTE(1) ENDT("vmcnt(6)")
    STG(tt + 4, 1) COMPUTE(2) ENDT("vmcnt(6)")
  }
  STG(14, 2) COMPUTE(0) ENDT("vmcnt(6)")
  STG(15, 0) COMPUTE(1) ENDT("vmcnt(6)")
  COMPUTE(2) ENDT("vmcnt(0)")
  COMPUTE(0)
#undef STG
#undef COMPUTE
#undef ENDT
}

// ===== GEMM mainloop B (R12): BM=128, BN=128, BK=64, 4 waves, 2 blocks/CU =====
__device__ __forceinline__ void mainloop_128x128v2(
    const unsigned short* __restrict__ Ab,   // A + m0*1024
    const unsigned short* __restrict__ Bb,   // B + n0*1024
    unsigned short* smem, f32x4 acc[4][4]) {
  const int tid = threadIdx.x;
  const int wave = tid >> 6, lane = tid & 63;
  const int lr = lane & 15, lg = lane >> 4;
  const int x7 = lr & 7;
  const int wr = wave >> 1, wc = wave & 1;
  const int rlo = lane >> 3;
  const int csw = 8 * ((lane & 7) ^ rlo);

#define STG(KT, BUF)                                                            \
  {                                                                             \
    unsigned short* la_ = smem + (BUF) * 16384;                                 \
    unsigned short* lb_ = la_ + 8192;                                           \
    _Pragma("unroll")                                                           \
    for (int c_ = 0; c_ < 4; ++c_) {                                            \
      const int ins_ = wave * 4 + c_;                                           \
      __builtin_amdgcn_global_load_lds(                                         \
          (const __attribute__((address_space(1))) void*)(Ab + (size_t)(ins_ * 8 + rlo) * 1024 + (KT) * 64 + csw), \
          (__attribute__((address_space(3))) void*)(la_ + ins_ * 512), 16, 0, 0); \
      __builtin_amdgcn_global_load_lds(                                         \
          (const __attribute__((address_space(1))) void*)(Bb + (size_t)(ins_ * 8 + rlo) * 1024 + (KT) * 64 + csw), \
          (__attribute__((address_space(3))) void*)(lb_ + ins_ * 512), 16, 0, 0); \
    }                                                                           \
  }

#define COMPUTE(BUF)                                                            \
  {                                                                             \
    const unsigned short* la_ = smem + (BUF) * 16384;                           \
    const unsigned short* ha_ = la_ + (wr * 64) * 64;                           \
    const unsigned short* hb_ = la_ + 8192 + (wc * 64) * 64;                    \
    _Pragma("unroll")                                                           \
    for (int ks_ = 0; ks_ < 2; ++ks_) {                                         \
      bf16x8 af_[4], bf_[4];                                                    \
      const int cu_ = (((ks_ * 4 + lg) ^ x7) << 3);                             \
      _Pragma("unroll")                                                         \
      for (int i_ = 0; i_ < 4; ++i_) {                                          \
        af_[i_] = *(const bf16x8*)(ha_ + (i_ * 16 + lr) * 64 + cu_);            \
        bf_[i_] = *(const bf16x8*)(hb_ + (i_ * 16 + lr) * 64 + cu_);            \
      }                                                                         \
      __builtin_amdgcn_s_setprio(1);                                            \
      _Pragma("unroll")                                                         \
      for (int mi_ = 0; mi_ < 4; ++mi_)                                         \
        _Pragma("unroll")                                                       \
        for (int ni_ = 0; ni_ < 4; ++ni_)                                       \
          acc[mi_][ni_] = mfma16(af_[mi_], bf_[ni_], acc[mi_][ni_]);            \
      __builtin_amdgcn_s_setprio(0);                                            \
    }                                                                           \
  }

  STG(0, 0)
  asm volatile("s_waitcnt vmcnt(0)" ::: "memory");
  __builtin_amdgcn_s_barrier();
  __builtin_amdgcn_sched_barrier(0);

#pragma unroll 2
  for (int t = 0; t < 16; ++t) {
    if (t < 15) {
      STG(t + 1, (t + 1) & 1)
      asm volatile("s_waitcnt vmcnt(8)" ::: "memory");
    } else {
      asm volatile("s_waitcnt vmcnt(0)" ::: "memory");
    }
    __builtin_amdgcn_s_barrier();
    __builtin_amdgcn_sched_barrier(0);
    COMPUTE(t & 1)
    __builtin_amdgcn_s_barrier();
    __builtin_amdgcn_sched_barrier(0);
  }
#undef STG
#undef COMPUTE
}

// ---------------- GEMM1: qkv proj (R11 structure, 63.8us), scatter to head layout ----------------
// grid 768 = 64 m-tiles x 12 n-tiles = 3.0 exact rounds at 1 block/CU.
// L2 mapping: XCD x owns m-tiles [8x,8x+8), m-minor / n-major.
__global__ __launch_bounds__(512) void gemm_qkv12(
    const unsigned short* __restrict__ A, const unsigned short* __restrict__ W,
    const float* __restrict__ bias,
    unsigned short* __restrict__ Qh, unsigned short* __restrict__ Kh,
    unsigned short* __restrict__ Vh) {
  extern __shared__ unsigned short smem[];
  const int bid = blockIdx.x;
  const int xcd = bid & 7, i = bid >> 3;          // i in [0,96)
  const int m0 = (xcd * 8 + (i & 7)) * 128;       // m-minor within XCD
  const int n0 = (i >> 3) * 256;                  // n-major

  f32x4 acc[4][4];
  const f32x4 z4 = {0.f, 0.f, 0.f, 0.f};
#pragma unroll
  for (int a = 0; a < 4; ++a)
#pragma unroll
    for (int b2 = 0; b2 < 4; ++b2) acc[a][b2] = z4;

  mainloop_128x256(A + (size_t)m0 * 1024, W + (size_t)n0 * 1024, smem, acc);

  const int lane = threadIdx.x & 63, wave = threadIdx.x >> 6;
  const int lr = lane & 15, lg = lane >> 4;
  const int wr = wave >> 2, wc = wave & 3;
#pragma unroll
  for (int mf = 0; mf < 4; ++mf)
#pragma unroll
    for (int nf = 0; nf < 4; ++nf)
#pragma unroll
      for (int j = 0; j < 4; ++j) {
        int m = m0 + wr * 64 + mf * 16 + lg * 4 + j;
        int f = n0 + wc * 64 + nf * 16 + lr;
        float v = acc[mf][nf][j] + bias[f];
        int t = m >> 3, b = m & 7;
        int e = f & 1023, h = e >> 6, d = e & 63;
        int which = f >> 10;
        size_t idx = ((size_t)(b * 16 + h) * T_DIM + t) * DH + d;
        if (which == 0)      Qh[idx] = f2bf(v * 0.18033688011111772f);  // 0.125*log2(e)
        else if (which == 1) Kh[idx] = f2bf(v);
        else                 Vh[idx] = f2bf(v);
      }
}

// ---------------- GEMM2: out = attn @ out_w^T + out_b (f32 out), R12 structure ----------------
// grid 512 = 64 m-tiles x 4 n-tiles = 1.0 exact round at 2 blocks/CU.
__global__ __launch_bounds__(256) void gemm_out13(
    const unsigned short* __restrict__ A, const unsigned short* __restrict__ W,
    const float* __restrict__ bias, float* __restrict__ out) {
  __shared__ unsigned short smem[32768];
  const int bid = blockIdx.x;
  const int xcd = bid & 7, i = bid >> 3;          // i in [0,64)
  const int m0 = (xcd * 8 + (i & 7)) * 128;
  const int n0 = (i >> 3) * 128;

  f32x4 acc[4][4];
  const f32x4 z4 = {0.f, 0.f, 0.f, 0.f};
#pragma unroll
  for (int a = 0; a < 4; ++a)
#pragma unroll
    for (int b2 = 0; b2 < 4; ++b2) acc[a][b2] = z4;

  mainloop_128x128v2(A + (size_t)m0 * 1024, W + (size_t)n0 * 1024, smem, acc);

  const int lane = threadIdx.x & 63, wave = threadIdx.x >> 6;
  const int lr = lane & 15, lg = lane >> 4;
  const int wr = wave >> 1, wc = wave & 1;
#pragma unroll
  for (int mf = 0; mf < 4; ++mf)
#pragma unroll
    for (int nf = 0; nf < 4; ++nf)
#pragma unroll
      for (int j = 0; j < 4; ++j) {
        int m = m0 + wr * 64 + mf * 16 + lg * 4 + j;
        int f = n0 + wc * 64 + nf * 16 + lr;
        out[(size_t)m * E_DIM + f] = acc[mf][nf][j] + bias[f];
      }
}

// ---------------- V transpose: [n][t][d] -> [n][d][t] ----------------
__global__ __launch_bounds__(256) void transpose_v(
    const unsigned short* __restrict__ Vh, unsigned short* __restrict__ Vt) {
  __shared__ unsigned short tile[64][72];
  const int n = blockIdx.x, t0 = blockIdx.y * 64;
  const int tid = threadIdx.x;
  const int r = tid >> 3, c8 = tid & 7;
#pragma unroll
  for (int it = 0; it < 2; ++it) {
    int row = it * 32 + r;
    bf16x8 v = *(const bf16x8*)(Vh + ((size_t)n * T_DIM + t0 + row) * DH + c8 * 8);
    *(bf16x8*)&tile[row][c8 * 8] = v;
  }
  __syncthreads();
#pragma unroll
  for (int it = 0; it < 2; ++it) {
    int d = it * 32 + r;
    bf16x8 ov;
#pragma unroll
    for (int jj = 0; jj < 8; ++jj) ov[jj] = (short)tile[c8 * 8 + jj][d];
    *(bf16x8*)(Vt + ((size_t)n * DH + d) * T_DIM + t0 + c8 * 8) = ov;
  }
}

// ---------------- flash attention v7: 256-q blocks x 8 waves (halved K/V staging) ----------------
// Same sync skeleton as v6 (proven): per 64-s tile {STAGE next -> counted vmcnt ->
// s_barrier -> compute -> s_barrier}. With 8 waves each wave issues 1 K + 1 V
// gload_lds per tile (was 2+2), so the counted wait drops vmcnt(4) -> vmcnt(2).
// K/V L2 read traffic per head halves (staged once per 256 q instead of per 128).
// grid 512 = 128 heads x 4 q-supertiles = 256 CU x 2 blocks (1.0 exact round).
__global__ __launch_bounds__(512) void flash_attn7(
    const unsigned short* __restrict__ Qh, const unsigned short* __restrict__ Kh,
    const unsigned short* __restrict__ Vt, unsigned short* __restrict__ attn) {
  __shared__ unsigned short lds[2][2][4096];   // [buf][K=0/V=1][64 rows x 64 elems]
  const int tid = threadIdx.x;
  const int wave = tid >> 6, lane = tid & 63;
  const int lq = lane & 31, hi = lane >> 5;
  const int bid = blockIdx.x;
  const int qs = 3 - (bid >> 7);       // q-supertile (256 rows), heavy first
  const int n = bid & 127;
  const int b = n >> 4, h = n & 15;
  const int q0w = qs * 256 + wave * 32;
  const int q = q0w + lq;
  const int nbb = 4 * qs + 4;          // KV 64-tiles this block processes
  const int mynb = (q0w + 95) >> 6;    // this wave computes tiles < mynb

  const unsigned short* kh_n = Kh + (size_t)n * (T_DIM * DH);
  const unsigned short* vt_n = Vt + (size_t)n * (DH * T_DIM);

  const int rlo = lane >> 3;
  const int csw = 8 * ((lane & 7) ^ rlo);

  // 8 waves: wave w stages rows [8w, 8w+8) of K and of V^T (1 instr each)
#define STAGE(S0, BUF)                                                          \
  {                                                                             \
    const int r_ = wave * 8 + rlo;                                              \
    __builtin_amdgcn_global_load_lds(                                           \
        (const __attribute__((address_space(1))) void*)(kh_n + (size_t)((S0) + r_) * DH + csw), \
        (__attribute__((address_space(3))) void*)(&lds[BUF][0][wave * 512]), 16, 0, 0); \
    __builtin_amdgcn_global_load_lds(                                           \
        (const __attribute__((address_space(1))) void*)(vt_n + (size_t)r_ * T_DIM + (S0) + csw), \
        (__attribute__((address_space(3))) void*)(&lds[BUF][1][wave * 512]), 16, 0, 0); \
  }

  bf16x8 qf[4];
  const unsigned short* qp = Qh + ((size_t)n * T_DIM + q) * DH + hi * 8;
#pragma unroll
  for (int kk = 0; kk < 4; ++kk) qf[kk] = *(const bf16x8*)(qp + kk * 16);

  f32x16 o0, o1;
#pragma unroll
  for (int r = 0; r < 16; ++r) { o0[r] = 0.f; o1[r] = 0.f; }
  float m_run = -1e30f, l_run = 0.f;

  STAGE(0, 0);
  asm volatile("s_waitcnt vmcnt(0)");
  __builtin_amdgcn_s_barrier();

  const int swzr = (lq & 7) << 4;

  for (int i = 0; i < nbb; ++i) {
    const int cur = i & 1;
    if (i + 1 < nbb) {
      STAGE((i + 1) * 64, cur ^ 1);
      asm volatile("s_waitcnt vmcnt(2)");   // own 2 prefetch loads stay in flight
    } else {
      asm volatile("s_waitcnt vmcnt(0)");
    }
    __builtin_amdgcn_s_barrier();
    __builtin_amdgcn_sched_barrier(0);

    if (i < mynb) {
      const int s0 = i * 64;
      const unsigned short* kb = lds[cur][0];
      const unsigned short* vb = lds[cur][1];
      f32x16 sA, sB;
#pragma unroll
      for (int r = 0; r < 16; ++r) { sA[r] = 0.f; sB[r] = 0.f; }
      __builtin_amdgcn_s_setprio(1);
#pragma unroll
      for (int kk = 0; kk < 4; ++kk) {
        const int cb = ((kk * 32 + hi * 16) ^ swzr) >> 1;
        bf16x8 ka = *(const bf16x8*)(kb + lq * 64 + cb);
        bf16x8 kbf = *(const bf16x8*)(kb + (32 + lq) * 64 + cb);
        sA = mfma32(ka, qf[kk], sA);
        sB = mfma32(kbf, qf[kk], sB);
      }
      __builtin_amdgcn_s_setprio(0);
      if (i == mynb - 1) {
#pragma unroll
        for (int r = 0; r < 16; ++r) {
          int sp = s0 + (r & 3) + 8 * (r >> 2) + 4 * hi;
          if (sp > q)      sA[r] = -10000.0f;
          if (sp + 32 > q) sB[r] = -10000.0f;
        }
      }
      float t0 = fmaxf(sA[0], sB[0]), t1 = fmaxf(sA[1], sB[1]);
      float t2 = fmaxf(sA[2], sB[2]), t3 = fmaxf(sA[3], sB[3]);
#pragma unroll
      for (int r = 4; r < 16; r += 4) {
        t0 = fmaxf(t0, fmaxf(sA[r], sB[r]));
        t1 = fmaxf(t1, fmaxf(sA[r + 1], sB[r + 1]));
        t2 = fmaxf(t2, fmaxf(sA[r + 2], sB[r + 2]));
        t3 = fmaxf(t3, fmaxf(sA[r + 3], sB[r + 3]));
      }
      float tmax = fmaxf(fmaxf(t0, t1), fmaxf(t2, t3));
      tmax = fmaxf(tmax, __shfl_xor(tmax, 32));
      if (__any(tmax - m_run > 11.5f)) {     // defer-max
        float m_new = fmaxf(m_run, tmax);
        float sc = exp2_hw(m_run - m_new);
        l_run *= sc;
#pragma unroll
        for (int r = 0; r < 16; ++r) { o0[r] *= sc; o1[r] *= sc; }
        m_run = m_new;
      }
      float r0 = 0.f, r1 = 0.f, r2 = 0.f, r3 = 0.f;
#pragma unroll
      for (int r = 0; r < 16; r += 4) {
        sA[r] = exp2_hw(sA[r] - m_run);         r0 += sA[r];
        sA[r + 1] = exp2_hw(sA[r + 1] - m_run); r1 += sA[r + 1];
        sA[r + 2] = exp2_hw(sA[r + 2] - m_run); r2 += sA[r + 2];
        sA[r + 3] = exp2_hw(sA[r + 3] - m_run); r3 += sA[r + 3];
      }
#pragma unroll
      for (int r = 0; r < 16; r += 4) {
        sB[r] = exp2_hw(sB[r] - m_run);         r0 += sB[r];
        sB[r + 1] = exp2_hw(sB[r + 1] - m_run); r1 += sB[r + 1];
        sB[r + 2] = exp2_hw(sB[r + 2] - m_run); r2 += sB[r + 2];
        sB[r + 3] = exp2_hw(sB[r + 3] - m_run); r3 += sB[r + 3];
      }
      float rs = (r0 + r1) + (r2 + r3);
      rs += __shfl_xor(rs, 32);
      l_run += rs;
      unsigned int pk[16];
#pragma unroll
      for (int ii = 0; ii < 8; ++ii) pk[ii]     = cvtpk_bf16(sA[2 * ii], sA[2 * ii + 1]);
#pragma unroll
      for (int ii = 0; ii < 8; ++ii) pk[8 + ii] = cvtpk_bf16(sB[2 * ii], sB[2 * ii + 1]);
      __builtin_amdgcn_s_setprio(1);
#pragma unroll
      for (int ks = 0; ks < 4; ++ks) {
        unsigned int A0 = pk[ks * 4 + 0], A1 = pk[ks * 4 + 1];
        unsigned int B0 = pk[ks * 4 + 2], B1 = pk[ks * 4 + 3];
        unsigned int xA0 = __shfl_xor(A0, 32), xA1 = __shfl_xor(A1, 32);
        unsigned int xB0 = __shfl_xor(B0, 32), xB1 = __shfl_xor(B1, 32);
        u32x4 uu;
        uu[0] = hi ? xB0 : A0;
        uu[1] = hi ? xB1 : A1;
        uu[2] = hi ? B0 : xA0;
        uu[3] = hi ? B1 : xA1;
        bf16x8 pf = __builtin_bit_cast(bf16x8, uu);
        const int cb = ((ks * 32 + hi * 16) ^ swzr) >> 1;
        bf16x8 v0 = *(const bf16x8*)(vb + lq * 64 + cb);
        bf16x8 v1 = *(const bf16x8*)(vb + (32 + lq) * 64 + cb);
        o0 = mfma32(v0, pf, o0);
        o1 = mfma32(v1, pf, o1);
      }
      __builtin_amdgcn_s_setprio(0);
    }
    __builtin_amdgcn_s_barrier();
  }
#undef STAGE

  const float inv = 1.0f / l_run;
  unsigned short* op = attn + ((size_t)q * B_DIM + b) * E_DIM + h * DH;
#pragma unroll
  for (int g = 0; g < 4; ++g) {
    u16x4 w0, w1;
#pragma unroll
    for (int jj = 0; jj < 4; ++jj) {
      w0[jj] = f2bf(o0[g * 4 + jj] * inv);
      w1[jj] = f2bf(o1[g * 4 + jj] * inv);
    }
    int d = 8 * g + 4 * hi;
    *(u16x4*)(op + d) = w0;
    *(u16x4*)(op + 32 + d) = w1;
  }
}

extern "C" void kernel_launch(void* const* d_in, const int* in_sizes, int n_in,
                              void* d_out, int out_size, void* d_ws, size_t ws_size,
                              hipStream_t stream) {
  const float* query = (const float*)d_in[0];
  const float* qkv_w = (const float*)d_in[1];
  const float* qkv_b = (const float*)d_in[2];
  const float* out_w = (const float*)d_in[3];
  const float* out_b = (const float*)d_in[4];
  float* out = (float*)d_out;

  char* ws = (char*)d_ws;
  unsigned short* Abf  = (unsigned short*)(ws);
  unsigned short* Wbf  = (unsigned short*)(ws + (size_t)(16u << 20));
  unsigned short* OWbf = (unsigned short*)(ws + (size_t)(22u << 20));
  unsigned short* Qh   = (unsigned short*)(ws + (size_t)(24u << 20));
  unsigned short* Kh   = (unsigned short*)(ws + (size_t)(40u << 20));
  unsigned short* Vh   = (unsigned short*)(ws + (size_t)(56u << 20));
  unsigned short* Vt   = (unsigned short*)(ws + (size_t)(72u << 20));
  unsigned short* attn = Abf;  // alias: query-bf16 dead after gemm_qkv12

  cast_all<<<12288, 256, 0, stream>>>(query, qkv_w, out_w, Abf, Wbf, OWbf);
  gemm_qkv12<<<768, 512, 147456, stream>>>(Abf, Wbf, qkv_b, Qh, Kh, Vh);
  transpose_v<<<dim3(128, 16), 256, 0, stream>>>(Vh, Vt);
  flash_attn7<<<512, 512, 0, stream>>>(Qh, Kh, Vt, attn);
  gemm_out13<<<512, 256, 0, stream>>>(attn, OWbf, out_b, out);
}